// Round 8
// baseline (432.791 us; speedup 1.0000x reference)
//
#include <hip/hip_runtime.h>

// PatchTrainer: paint 100 filled circles (last-wins) over a 3x4096x4096 fp32 image.
// Per pixel: out = colors[max covering dot] else patch. Write-streaming.
// R4: descending scan + wave early-exit       -> NEUTRAL (loop off critical path)
// R5: plain stores, 8/CU, ballot compaction   -> ~NEUTRAL (-4 us, confounded)
// R6b: plane-per-block, 1D grid, 24/CU        -> ~NEUTRAL (-2 us)
// R7: nontemporal stores (clean A/B)          -> -4 us (RFO minor, not the limiter)
// R8: FILL-CLONE structure. Block = 8 complete rows of one plane = one contiguous
//     128 KiB slab; store address = slab + it*1024 + t*4 (block-linear, identical
//     to rocclr fill's 6.5 TB/s pattern). Grid 1536 = 6/CU: all blocks resident at
//     launch -> ZERO block churn, dot setup (600 scattered loads + 2 barriers per
//     block) runs once, in parallel, amortized over 4x more bytes. Culling is
//     y-band only; wave-uniform row cull + descending early-exit bound the scan.

#define IMG   4096
#define ND    100
#define ROWS  8                       // full-width rows per block
#define NBB   (IMG / ROWS)            // 512 blocks per plane

typedef float vfloat4 __attribute__((ext_vector_type(4)));

__global__ __launch_bounds__(256) void patch_dots_kernel(
    const float* __restrict__ patch,    // [3][4096][4096]
    const float* __restrict__ centers,  // [100][2] (x, y)
    const float* __restrict__ radii,    // [100]
    const float* __restrict__ colors,   // [100][3]
    float* __restrict__ out)            // [3][4096][4096]
{
    __shared__ float  s_xc[ND], s_yc[ND], s_r2[ND], s_col[ND];
    __shared__ int    s_list[ND];
    __shared__ unsigned long long s_mask[2];
    __shared__ int    s_cnt;

    // Plane-major: blocks 0..511 -> plane 0 (phase separation preserved).
    const int bid = blockIdx.x;
    const int z   = bid / NBB;            // color plane (uniform per block)
    const int ty0 = (bid % NBB) * ROWS;   // first row of slab

    const int t    = threadIdx.x;
    const int lane = t & 63;
    const int w    = t >> 6;

    // Stage dot params in LDS + y-band cull (full-width slab: x always inside).
    int flag = 0;
    if (t < ND) {
        // Bit-exact replication of the reference's fp32 math:
        float xc = floorf(centers[2 * t]     * 4096.0f);
        float yc = floorf(centers[2 * t + 1] * 4096.0f);
        float r  = floorf(radii[t] * (4096.0f / 5.0f));
        float r2 = r * r;
        s_xc[t] = xc; s_yc[t] = yc; s_r2[t] = r2;
        s_col[t] = colors[3 * t + z];
        // Band test: nearest row of [ty0, ty0+ROWS-1] to yc.
        float cy = fminf(fmaxf(yc, (float)ty0), (float)(ty0 + ROWS - 1));
        float dy = yc - cy;
        flag = (dy * dy <= r2) ? 1 : 0;
    }
    // Ordered compaction via ballot (waves 0,1 hold dots 0..63, 64..99).
    if (t < 128) {
        unsigned long long m = __ballot(flag != 0);
        if (lane == 0) s_mask[w] = m;
    }
    __syncthreads();
    {
        const unsigned long long m0 = s_mask[0];
        if (flag) {
            const unsigned long long mw = s_mask[w];
            int pos = __popcll(mw & ((1ull << lane) - 1)) + (w ? __popcll(m0) : 0);
            s_list[pos] = t;
        }
        if (t == 0) s_cnt = __popcll(m0) + __popcll(s_mask[1]);
    }
    __syncthreads();
    const int cnt = s_cnt;

    const size_t slab = (size_t)z * IMG * IMG + (size_t)ty0 * IMG;

    // 32 iterations x 1024 px (256 thr x float4): linear walk over the 128 KiB slab.
    for (int it = 0; it < ROWS * IMG / 1024; ++it) {
        const int q   = it * 1024 + t * 4;     // pixel offset within slab
        const int x0  = q & (IMG - 1);
        const int yof = q >> 12;               // 0..ROWS-1 (wave-uniform: 256px < row)
        const float fy  = (float)(ty0 + yof);
        const float fx0 = (float)x0;
        const float fx1 = (float)(x0 + 1);
        const float fx2 = (float)(x0 + 2);
        const float fx3 = (float)(x0 + 3);

        // Scan dots from HIGHEST index down: first hit == last-drawn winner.
        int b0 = -1, b1 = -1, b2 = -1, b3 = -1;
        for (int k = cnt - 1; k >= 0; --k) {
            const int   i  = s_list[k];
            const float dy = fy - s_yc[i];
            // hit iff dx*dx <= r2 - dy*dy (exact-integer fp32 region: equivalent
            // to dx*dx + dy*dy <= r2, the reference's comparison)
            const float t2 = s_r2[i] - dy * dy;
            if (t2 < 0.f) continue;          // fy uniform per wave -> coherent skip
            const float xc = s_xc[i];
            const float dx0 = fx0 - xc;
            const float dx1 = fx1 - xc;
            const float dx2 = fx2 - xc;
            const float dx3 = fx3 - xc;
            if (b0 < 0 && dx0 * dx0 <= t2) b0 = i;
            if (b1 < 0 && dx1 * dx1 <= t2) b1 = i;
            if (b2 < 0 && dx2 * dx2 <= t2) b2 = i;
            if (b3 < 0 && dx3 * dx3 <= t2) b3 = i;
            if (__all((b0 | b1 | b2 | b3) >= 0)) break;
        }

        const size_t base = slab + (size_t)q;   // linear: yof*IMG + x0 == q

        // Patch (this plane only) needed where no dot covers (~1.5% of pixels).
        float4 p = make_float4(0.f, 0.f, 0.f, 0.f);
        if ((b0 | b1 | b2 | b3) < 0) {
            const vfloat4 pv = __builtin_nontemporal_load((const vfloat4*)(patch + base));
            p = make_float4(pv.x, pv.y, pv.z, pv.w);
        }

        vfloat4 o;
        o.x = (b0 >= 0) ? s_col[b0] : p.x;
        o.y = (b1 >= 0) ? s_col[b1] : p.y;
        o.z = (b2 >= 0) ? s_col[b2] : p.z;
        o.w = (b3 >= 0) ? s_col[b3] : p.w;

        __builtin_nontemporal_store(o, (vfloat4*)(out + base));
    }
}

extern "C" void kernel_launch(void* const* d_in, const int* in_sizes, int n_in,
                              void* d_out, int out_size, void* d_ws, size_t ws_size,
                              hipStream_t stream) {
    const float* patch   = (const float*)d_in[0];
    const float* centers = (const float*)d_in[1];
    const float* radii   = (const float*)d_in[2];
    const float* colors  = (const float*)d_in[3];
    float* out = (float*)d_out;

    dim3 grid(3 * NBB);   // 1536 blocks (6/CU) — all resident, zero churn
    dim3 block(256);
    patch_dots_kernel<<<grid, block, 0, stream>>>(patch, centers, radii, colors, out);
}

// Round 9
// 302.709 us; speedup vs baseline: 1.4297x; 1.4297x over previous
//
#include <hip/hip_runtime.h>

// PatchTrainer: paint 100 filled circles (last-wins) over a 3x4096x4096 fp32 image.
// Per pixel: out = colors[max covering dot] else patch. Write-streaming.
// R4: descending scan + wave early-exit       -> NEUTRAL (not VALU-throughput-bound)
// R7: nontemporal stores (clean A/B)          -> -4 us (best: 304.4 us)
// R8: fill-clone slabs, band cull             -> REGRESSION 433 us, but first kernel
//     profile: 184 us @ 1.1 TB/s (14%), VALUBusy 40%, FETCH 2 MB => LATENCY-bound.
//     Culprit: dot loop's double-indirect LDS chain (s_list[k] -> s_xc[i]) + a
//     data-dependent `continue` that blocks unroll/pipelining => ~2 serial LDS
//     latencies (~240 cyc) per dot.
// R9: R7 structure + latency-free loop: compaction writes COMPACTED PARAM ARRAYS
//     (no indirection; loads at compile-time offsets of k) + branchless body
//     (t2<0 can't hit anyway since dx^2>=0) so the compiler unrolls & batches
//     ds_reads. Early-exit kept for heavy central tiles.

#define IMG  4096
#define ND   100
#define TW   256   // tile width  (64 lanes x float4 = one full row per wave)
#define TH   32    // tile height (4 waves, 8 iterations of 4 rows)
#define NBX  (IMG / TW)          // 16
#define NBY  (IMG / TH)          // 128

typedef float vfloat4 __attribute__((ext_vector_type(4)));

__global__ __launch_bounds__(256) void patch_dots_kernel(
    const float* __restrict__ patch,    // [3][4096][4096]
    const float* __restrict__ centers,  // [100][2] (x, y)
    const float* __restrict__ radii,    // [100]
    const float* __restrict__ colors,   // [100][3]
    float* __restrict__ out)            // [3][4096][4096]
{
    // Compacted per-tile dot params (ascending original order preserved).
    __shared__ float s_cxc[ND], s_cyc[ND], s_cr2[ND], s_ccol[ND];
    __shared__ unsigned long long s_mask[2];
    __shared__ int s_cnt;

    // 1D grid decode: x fastest, then y-tile, plane slowest (phase-separated).
    const int bid = blockIdx.x;
    const int bx  = bid % NBX;
    const int by  = (bid / NBX) % NBY;
    const int z   = bid / (NBX * NBY);   // color plane

    const int tx0 = bx * TW;
    const int ty0 = by * TH;
    const int t   = threadIdx.x;
    const int lane = t & 63;
    const int w    = t >> 6;

    const size_t plane = (size_t)z * IMG * IMG;

    // Cull + stage: params stay in registers, compaction scatters them to LDS.
    int flag = 0;
    float xc = 0.f, yc = 0.f, r2 = 0.f, col = 0.f;
    if (t < ND) {
        // Bit-exact replication of the reference's fp32 math:
        xc = floorf(centers[2 * t]     * 4096.0f);
        yc = floorf(centers[2 * t + 1] * 4096.0f);
        float r = floorf(radii[t] * (4096.0f / 5.0f));
        r2 = r * r;
        col = colors[3 * t + z];
        // Nearest pixel of this tile to the (integer-valued) center:
        float cx = fminf(fmaxf(xc, (float)tx0), (float)(tx0 + TW - 1));
        float cy = fminf(fmaxf(yc, (float)ty0), (float)(ty0 + TH - 1));
        float dx = xc - cx, dy = yc - cy;
        flag = (dx * dx + dy * dy <= r2) ? 1 : 0;
    }
    // Ordered compaction via ballot (waves 0,1 hold dots 0..63, 64..99).
    if (t < 128) {
        unsigned long long m = __ballot(flag != 0);
        if (lane == 0) s_mask[w] = m;
    }
    __syncthreads();
    {
        const unsigned long long m0 = s_mask[0];
        if (flag) {
            const unsigned long long mw = s_mask[w];
            int pos = __popcll(mw & ((1ull << lane) - 1)) + (w ? __popcll(m0) : 0);
            s_cxc[pos] = xc; s_cyc[pos] = yc; s_cr2[pos] = r2; s_ccol[pos] = col;
        }
        if (t == 0) s_cnt = __popcll(m0) + __popcll(s_mask[1]);
    }
    __syncthreads();
    const int cnt = s_cnt;

    const int x0   = tx0 + lane * 4;
    const float fx0 = (float)x0;
    const float fx1 = (float)(x0 + 1);
    const float fx2 = (float)(x0 + 2);
    const float fx3 = (float)(x0 + 3);

    for (int it = 0; it < TH / 4; ++it) {
        const int   y  = ty0 + it * 4 + w;
        const float fy = (float)y;

        // Descending scan: first hit == last-drawn winner. Branchless body
        // (no dependent loads, no continue) -> compiler pipelines ds_reads.
        int b0 = -1, b1 = -1, b2 = -1, b3 = -1;
        for (int k = cnt - 1; k >= 0; --k) {
            const float yck = s_cyc[k];
            const float r2k = s_cr2[k];
            const float xck = s_cxc[k];
            const float dy  = fy - yck;
            const float t2  = r2k - dy * dy;   // t2<0 => no x can hit (dx*dx>=0)
            const float dx0 = fx0 - xck;
            const float dx1 = fx1 - xck;
            const float dx2 = fx2 - xck;
            const float dx3 = fx3 - xck;
            if (b0 < 0 && dx0 * dx0 <= t2) b0 = k;
            if (b1 < 0 && dx1 * dx1 <= t2) b1 = k;
            if (b2 < 0 && dx2 * dx2 <= t2) b2 = k;
            if (b3 < 0 && dx3 * dx3 <= t2) b3 = k;
            if (__all((b0 | b1 | b2 | b3) >= 0)) break;
        }

        const size_t base = plane + (size_t)y * IMG + x0;

        // Patch (this plane only) needed where no dot covers (~1.5% of pixels).
        float4 p = make_float4(0.f, 0.f, 0.f, 0.f);
        if ((b0 | b1 | b2 | b3) < 0) {
            const vfloat4 pv = __builtin_nontemporal_load((const vfloat4*)(patch + base));
            p = make_float4(pv.x, pv.y, pv.z, pv.w);
        }

        vfloat4 o;
        o.x = (b0 >= 0) ? s_ccol[b0] : p.x;
        o.y = (b1 >= 0) ? s_ccol[b1] : p.y;
        o.z = (b2 >= 0) ? s_ccol[b2] : p.z;
        o.w = (b3 >= 0) ? s_ccol[b3] : p.w;

        __builtin_nontemporal_store(o, (vfloat4*)(out + base));
    }
}

extern "C" void kernel_launch(void* const* d_in, const int* in_sizes, int n_in,
                              void* d_out, int out_size, void* d_ws, size_t ws_size,
                              hipStream_t stream) {
    const float* patch   = (const float*)d_in[0];
    const float* centers = (const float*)d_in[1];
    const float* radii   = (const float*)d_in[2];
    const float* colors  = (const float*)d_in[3];
    float* out = (float*)d_out;

    dim3 grid(NBX * NBY * 3);  // 6144 blocks, 1D (24/CU)
    dim3 block(256);
    patch_dots_kernel<<<grid, block, 0, stream>>>(patch, centers, radii, colors, out);
}